// Round 1
// baseline (204.097 us; speedup 1.0000x reference)
//
#include <hip/hip_runtime.h>
#include <math.h>

#define BATCH 4
#define SEQ   512
#define IND   256
#define NH    8
#define DKV   32
#define BH    32   // BATCH*NH
#define NTOK  2048 // BATCH*SEQ

// ---------------- zero am accumulator ----------------
__global__ void zero_am_kernel(float* __restrict__ am) {
    int i = blockIdx.x * 256 + threadIdx.x;
    if (i < BATCH * SEQ) am[i] = 0.0f;
}

// ---------------- LayerNorm ----------------
__global__ void ln_kernel(const float* __restrict__ x,
                          const float* __restrict__ gamma,
                          const float* __restrict__ beta,
                          float* __restrict__ xn) {
    int row = blockIdx.x;
    int t = threadIdx.x;
    float v = x[row * IND + t];
    float s = v, s2 = v * v;
    #pragma unroll
    for (int o = 32; o > 0; o >>= 1) {
        s  += __shfl_xor(s,  o, 64);
        s2 += __shfl_xor(s2, o, 64);
    }
    __shared__ float ls[4], ls2[4];
    int w = t >> 6;
    if ((t & 63) == 0) { ls[w] = s; ls2[w] = s2; }
    __syncthreads();
    s  = ls[0] + ls[1] + ls[2] + ls[3];
    s2 = ls2[0] + ls2[1] + ls2[2] + ls2[3];
    float mu  = s * (1.0f / IND);
    float var = s2 * (1.0f / IND) - mu * mu;
    float r = rsqrtf(var + 1e-6f);
    xn[row * IND + t] = (v - mu) * r * gamma[t] + beta[t];
}

// ---------------- Projections: xn @ {w_q,w_k,w_v} -> Q,K,V  [bh][l][32] ----------------
__global__ void proj_kernel(const float* __restrict__ xn,
                            const float* __restrict__ wq,
                            const float* __restrict__ wk,
                            const float* __restrict__ wv,
                            float* __restrict__ Q,
                            float* __restrict__ K,
                            float* __restrict__ V) {
    int which = blockIdx.y;
    const float* W = (which == 0) ? wq : (which == 1) ? wk : wv;
    float* O = (which == 0) ? Q : (which == 1) ? K : V;
    int r0 = blockIdx.x * 16;
    int col = threadIdx.x;
    float acc[16];
    #pragma unroll
    for (int r = 0; r < 16; r++) acc[r] = 0.0f;
    for (int kk = 0; kk < IND; kk++) {
        float wv_ = W[kk * IND + col];
        #pragma unroll
        for (int r = 0; r < 16; r++)
            acc[r] = fmaf(xn[(r0 + r) * IND + kk], wv_, acc[r]);
    }
    float scale = (which == 0) ? 0.17677669529663687f : 1.0f;  // q /= sqrt(32)
    int h = col >> 5, d = col & 31;
    #pragma unroll
    for (int r = 0; r < 16; r++) {
        int tok = r0 + r;
        int b = tok >> 9, l = tok & 511;
        O[(((b << 3) + h) * SEQ + l) * DKV + d] = acc[r] * scale;
    }
}

// ---------------- Attention: L1-distance scores + softmax + PV + am accumulation ----
// grid: (SEQ/16, BH); block: 256
__global__ void attn_kernel(const float* __restrict__ Q,
                            const float* __restrict__ Km,
                            const float* __restrict__ V,
                            float* __restrict__ attn_out,  // [tok][256], col = h*32+d
                            float* __restrict__ am) {      // [b][512]
    __shared__ __align__(16) float S[16][516];
    __shared__ __align__(16) float T[128][36];

    int gy = blockIdx.y;                  // bh
    int i0 = blockIdx.x * 16;
    int t = threadIdx.x;
    int b = gy >> 3, h = gy & 7;
    const float* Qb = Q + gy * SEQ * DKV;
    const float* Kb = Km + gy * SEQ * DKV;
    const float* Vb = V + gy * SEQ * DKV;

    int ti = t >> 4;     // i in 0..15
    int tj = t & 15;     // j sub-lane

    // K row for this thread's i, in registers
    float4 kreg[8];
    #pragma unroll
    for (int c = 0; c < 8; c++)
        kreg[c] = *(const float4*)&Kb[(i0 + ti) * DKV + c * 4];

    // ---- Phase 1: S[i][j] = mean_d |q_j[d] - k_i[d]| ----
    for (int jt = 0; jt < 4; jt++) {
        #pragma unroll
        for (int n = 0; n < 4; n++) {
            int cidx = t + n * 256;           // 0..1023 = 128 rows * 8 chunks
            int row = cidx >> 3, ch = cidx & 7;
            *(float4*)&T[row][ch * 4] =
                *(const float4*)&Qb[(jt * 128 + row) * DKV + ch * 4];
        }
        __syncthreads();
        #pragma unroll
        for (int m = 0; m < 8; m++) {
            int jl = tj + m * 16;
            float acc = 0.0f;
            #pragma unroll
            for (int c = 0; c < 8; c++) {
                float4 qv = *(const float4*)&T[jl][c * 4];
                acc += fabsf(qv.x - kreg[c].x) + fabsf(qv.y - kreg[c].y)
                     + fabsf(qv.z - kreg[c].z) + fabsf(qv.w - kreg[c].w);
            }
            S[ti][jt * 128 + jl] = acc * (1.0f / 32.0f);
        }
        __syncthreads();
    }

    // ---- Phase 2: row softmax (16 threads per row, 32 cols each) ----
    float vals[32];
    float mx = -1e30f;
    #pragma unroll
    for (int m = 0; m < 32; m++) {
        vals[m] = S[ti][tj + m * 16];
        mx = fmaxf(mx, vals[m]);
    }
    #pragma unroll
    for (int o = 1; o < 16; o <<= 1) mx = fmaxf(mx, __shfl_xor(mx, o, 64));
    float sum = 0.0f;
    #pragma unroll
    for (int m = 0; m < 32; m++) {
        vals[m] = expf(vals[m] - mx);
        sum += vals[m];
    }
    #pragma unroll
    for (int o = 1; o < 16; o <<= 1) sum += __shfl_xor(sum, o, 64);
    float inv = 1.0f / sum;
    #pragma unroll
    for (int m = 0; m < 32; m++) S[ti][tj + m * 16] = vals[m] * inv;
    __syncthreads();

    // ---- am partial: col sums over i ----
    #pragma unroll
    for (int n = 0; n < 2; n++) {
        int j = t + n * 256;
        float cs = 0.0f;
        #pragma unroll
        for (int i = 0; i < 16; i++) cs += S[i][j];
        atomicAdd(&am[b * SEQ + j], cs * 0.125f);  // /H
    }

    // ---- Phase 3: O[d,i] = sum_j P[i,j] * V[d,j]  (register-blocked 4x4) ----
    int jg = t >> 5;            // 0..7 : j sub-range within each tile
    int u = t & 31;
    int i4 = (u >> 3) * 4;      // 0,4,8,12
    int d4 = (u & 7) * 4;       // 0..28
    float acc3[4][4];
    #pragma unroll
    for (int r = 0; r < 4; r++)
        #pragma unroll
        for (int c = 0; c < 4; c++) acc3[r][c] = 0.0f;

    for (int jt = 0; jt < 4; jt++) {
        #pragma unroll
        for (int n = 0; n < 4; n++) {
            int cidx = t + n * 256;
            int row = cidx >> 3, ch = cidx & 7;
            *(float4*)&T[row][ch * 4] =
                *(const float4*)&Vb[(jt * 128 + row) * DKV + ch * 4];
        }
        __syncthreads();
        #pragma unroll
        for (int n = 0; n < 16; n++) {
            int jl = jg * 16 + n;
            int j = jt * 128 + jl;
            float p0 = S[i4 + 0][j];
            float p1 = S[i4 + 1][j];
            float p2 = S[i4 + 2][j];
            float p3 = S[i4 + 3][j];
            float4 vv = *(const float4*)&T[jl][d4];
            acc3[0][0] = fmaf(p0, vv.x, acc3[0][0]);
            acc3[0][1] = fmaf(p0, vv.y, acc3[0][1]);
            acc3[0][2] = fmaf(p0, vv.z, acc3[0][2]);
            acc3[0][3] = fmaf(p0, vv.w, acc3[0][3]);
            acc3[1][0] = fmaf(p1, vv.x, acc3[1][0]);
            acc3[1][1] = fmaf(p1, vv.y, acc3[1][1]);
            acc3[1][2] = fmaf(p1, vv.z, acc3[1][2]);
            acc3[1][3] = fmaf(p1, vv.w, acc3[1][3]);
            acc3[2][0] = fmaf(p2, vv.x, acc3[2][0]);
            acc3[2][1] = fmaf(p2, vv.y, acc3[2][1]);
            acc3[2][2] = fmaf(p2, vv.z, acc3[2][2]);
            acc3[2][3] = fmaf(p2, vv.w, acc3[2][3]);
            acc3[3][0] = fmaf(p3, vv.x, acc3[3][0]);
            acc3[3][1] = fmaf(p3, vv.y, acc3[3][1]);
            acc3[3][2] = fmaf(p3, vv.z, acc3[3][2]);
            acc3[3][3] = fmaf(p3, vv.w, acc3[3][3]);
        }
        __syncthreads();
    }

    // reduce 8 j-group partials via LDS (reuse S storage)
    float* Sf = &S[0][0];
    #pragma unroll
    for (int r = 0; r < 4; r++)
        #pragma unroll
        for (int c = 0; c < 4; c++)
            Sf[jg * 512 + (i4 + r) * 32 + d4 + c] = acc3[r][c];
    __syncthreads();
    #pragma unroll
    for (int n = 0; n < 2; n++) {
        int o = t + n * 256;
        int ii = o >> 5, d = o & 31;
        float sm = 0.0f;
        #pragma unroll
        for (int g = 0; g < 8; g++) sm += Sf[g * 512 + o];
        attn_out[(b * SEQ + i0 + ii) * IND + h * 32 + d] = sm;
    }
}

// ---------------- FC + residual ----------------
__global__ void fc_kernel(const float* __restrict__ ao,
                          const float* __restrict__ wfc,
                          const float* __restrict__ xn,
                          float* __restrict__ out) {
    int r0 = blockIdx.x * 16;
    int col = threadIdx.x;
    float acc[16];
    #pragma unroll
    for (int r = 0; r < 16; r++) acc[r] = 0.0f;
    for (int kk = 0; kk < IND; kk++) {
        float wv_ = wfc[kk * IND + col];
        #pragma unroll
        for (int r = 0; r < 16; r++)
            acc[r] = fmaf(ao[(r0 + r) * IND + kk], wv_, acc[r]);
    }
    #pragma unroll
    for (int r = 0; r < 16; r++)
        out[(r0 + r) * IND + col] = acc[r] + xn[(r0 + r) * IND + col];
}

// ---------------- am min-max normalize ----------------
__global__ void amnorm_kernel(const float* __restrict__ am,
                              float* __restrict__ out_am) {
    int b = blockIdx.x;
    int t = threadIdx.x;
    float v0 = am[b * SEQ + t];
    float v1 = am[b * SEQ + t + 256];
    float mn = fminf(v0, v1), mx = fmaxf(v0, v1);
    #pragma unroll
    for (int o = 32; o > 0; o >>= 1) {
        mn = fminf(mn, __shfl_xor(mn, o, 64));
        mx = fmaxf(mx, __shfl_xor(mx, o, 64));
    }
    __shared__ float lmn[4], lmx[4];
    int w = t >> 6;
    if ((t & 63) == 0) { lmn[w] = mn; lmx[w] = mx; }
    __syncthreads();
    mn = fminf(fminf(lmn[0], lmn[1]), fminf(lmn[2], lmn[3]));
    mx = fmaxf(fmaxf(lmx[0], lmx[1]), fmaxf(lmx[2], lmx[3]));
    float inv = 1.0f / (mx - mn);
    out_am[b * SEQ + t]       = (v0 - mn) * inv;
    out_am[b * SEQ + t + 256] = (v1 - mn) * inv;
}

extern "C" void kernel_launch(void* const* d_in, const int* in_sizes, int n_in,
                              void* d_out, int out_size, void* d_ws, size_t ws_size,
                              hipStream_t stream) {
    (void)in_sizes; (void)n_in; (void)out_size; (void)ws_size;
    const float* x     = (const float*)d_in[0];
    const float* w_q   = (const float*)d_in[1];
    const float* w_k   = (const float*)d_in[2];
    const float* w_v   = (const float*)d_in[3];
    const float* w_fc  = (const float*)d_in[4];
    const float* gamma = (const float*)d_in[5];
    const float* beta  = (const float*)d_in[6];
    float* out = (float*)d_out;

    float* ws = (float*)d_ws;
    float* xn = ws;                          // 2048*256
    float* Qw = xn + NTOK * IND;             // 32*512*32
    float* Kw = Qw + BH * SEQ * DKV;
    float* Vw = Kw + BH * SEQ * DKV;
    float* AO = Vw + BH * SEQ * DKV;         // 2048*256
    float* AM = AO + NTOK * IND;             // 4*512

    hipLaunchKernelGGL(zero_am_kernel, dim3(8), dim3(256), 0, stream, AM);
    hipLaunchKernelGGL(ln_kernel, dim3(NTOK), dim3(256), 0, stream, x, gamma, beta, xn);
    hipLaunchKernelGGL(proj_kernel, dim3(128, 3), dim3(256), 0, stream,
                       xn, w_q, w_k, w_v, Qw, Kw, Vw);
    hipLaunchKernelGGL(attn_kernel, dim3(SEQ / 16, BH), dim3(256), 0, stream,
                       Qw, Kw, Vw, AO, AM);
    hipLaunchKernelGGL(fc_kernel, dim3(NTOK / 16), dim3(256), 0, stream,
                       AO, w_fc, xn, out);
    hipLaunchKernelGGL(amnorm_kernel, dim3(BATCH), dim3(256), 0, stream,
                       AM, out + NTOK * IND);
}

// Round 2
// 99.096 us; speedup vs baseline: 2.0596x; 2.0596x over previous
//
#include <hip/hip_runtime.h>
#include <math.h>

#define BATCH 4
#define SEQ   512
#define IND   256
#define NH    8
#define DKV   32
#define BH    32   // BATCH*NH
#define NTOK  2048 // BATCH*SEQ

// ---------------- zero am accumulator ----------------
__global__ void zero_am_kernel(float* __restrict__ am) {
    int i = blockIdx.x * 256 + threadIdx.x;
    if (i < BATCH * SEQ) am[i] = 0.0f;
}

// ---------------- LayerNorm ----------------
__global__ void ln_kernel(const float* __restrict__ x,
                          const float* __restrict__ gamma,
                          const float* __restrict__ beta,
                          float* __restrict__ xn) {
    int row = blockIdx.x;
    int t = threadIdx.x;
    float v = x[row * IND + t];
    float s = v, s2 = v * v;
    #pragma unroll
    for (int o = 32; o > 0; o >>= 1) {
        s  += __shfl_xor(s,  o, 64);
        s2 += __shfl_xor(s2, o, 64);
    }
    __shared__ float ls[4], ls2[4];
    int w = t >> 6;
    if ((t & 63) == 0) { ls[w] = s; ls2[w] = s2; }
    __syncthreads();
    s  = ls[0] + ls[1] + ls[2] + ls[3];
    s2 = ls2[0] + ls2[1] + ls2[2] + ls2[3];
    float mu  = s * (1.0f / IND);
    float var = s2 * (1.0f / IND) - mu * mu;
    float r = rsqrtf(var + 1e-6f);
    xn[row * IND + t] = (v - mu) * r * gamma[t] + beta[t];
}

// ---------------- 64x64 tiled fp32 GEMM core (K=256, BK=32, double-buffered) ----
// A: [*][256] row-major; B: [256][ldb] row-major. Thread (tx,ty) computes
// rows m0+ty*4..+3, cols n0+tx*4..+3 into acc[4][4].
__device__ __forceinline__ void gemm_tile_64(const float* __restrict__ A,
                                             const float* __restrict__ B,
                                             int m0, int n0, int ldb,
                                             float acc[4][4]) {
    __shared__ __align__(16) float As[2][32][68];  // [kk][m], transposed, +4 pad
    __shared__ __align__(16) float Bs[2][32][68];  // [kk][n], +4 pad
    const int t  = threadIdx.x;
    const int tx = t & 15, ty = t >> 4;
    const int am = t >> 3, ac = (t & 7) * 4;       // A staging: row am, k-chunk ac
    const int bk = t >> 4, bn = (t & 15) * 4;      // B staging

    float4 a0, a1, b0, b1;
    auto loadG = [&](int kc) {
        a0 = *(const float4*)&A[(m0 + am) * IND + kc * 32 + ac];
        a1 = *(const float4*)&A[(m0 + 32 + am) * IND + kc * 32 + ac];
        b0 = *(const float4*)&B[(kc * 32 + bk) * ldb + n0 + bn];
        b1 = *(const float4*)&B[(kc * 32 + 16 + bk) * ldb + n0 + bn];
    };
    auto storeL = [&](int buf) {
        As[buf][ac + 0][am] = a0.x; As[buf][ac + 1][am] = a0.y;
        As[buf][ac + 2][am] = a0.z; As[buf][ac + 3][am] = a0.w;
        As[buf][ac + 0][am + 32] = a1.x; As[buf][ac + 1][am + 32] = a1.y;
        As[buf][ac + 2][am + 32] = a1.z; As[buf][ac + 3][am + 32] = a1.w;
        *(float4*)&Bs[buf][bk][bn]      = b0;
        *(float4*)&Bs[buf][16 + bk][bn] = b1;
    };

    loadG(0); storeL(0);
    for (int kc = 0; kc < 8; kc++) {
        __syncthreads();
        if (kc < 7) loadG(kc + 1);
        const int buf = kc & 1;
        #pragma unroll
        for (int kk = 0; kk < 32; kk++) {
            float4 av = *(const float4*)&As[buf][kk][ty * 4];
            float4 bv = *(const float4*)&Bs[buf][kk][tx * 4];
            acc[0][0] = fmaf(av.x, bv.x, acc[0][0]);
            acc[0][1] = fmaf(av.x, bv.y, acc[0][1]);
            acc[0][2] = fmaf(av.x, bv.z, acc[0][2]);
            acc[0][3] = fmaf(av.x, bv.w, acc[0][3]);
            acc[1][0] = fmaf(av.y, bv.x, acc[1][0]);
            acc[1][1] = fmaf(av.y, bv.y, acc[1][1]);
            acc[1][2] = fmaf(av.y, bv.z, acc[1][2]);
            acc[1][3] = fmaf(av.y, bv.w, acc[1][3]);
            acc[2][0] = fmaf(av.z, bv.x, acc[2][0]);
            acc[2][1] = fmaf(av.z, bv.y, acc[2][1]);
            acc[2][2] = fmaf(av.z, bv.z, acc[2][2]);
            acc[2][3] = fmaf(av.z, bv.w, acc[2][3]);
            acc[3][0] = fmaf(av.w, bv.x, acc[3][0]);
            acc[3][1] = fmaf(av.w, bv.y, acc[3][1]);
            acc[3][2] = fmaf(av.w, bv.z, acc[3][2]);
            acc[3][3] = fmaf(av.w, bv.w, acc[3][3]);
        }
        if (kc < 7) { __syncthreads(); storeL((kc + 1) & 1); }
    }
}

// ---------------- Projections: xn @ {w_q,w_k,w_v} -> Q,K,V [bh][l][32] -------
// grid (32, 4, 3), block 256
__global__ __launch_bounds__(256) void proj_kernel(
        const float* __restrict__ xn,
        const float* __restrict__ wq, const float* __restrict__ wk,
        const float* __restrict__ wv,
        float* __restrict__ Q, float* __restrict__ K, float* __restrict__ V) {
    int which = blockIdx.z;
    const float* W = (which == 0) ? wq : (which == 1) ? wk : wv;
    float* O = (which == 0) ? Q : (which == 1) ? K : V;
    int m0 = blockIdx.x * 64, n0 = blockIdx.y * 64;
    float acc[4][4] = {};
    gemm_tile_64(xn, W, m0, n0, IND, acc);
    float scale = (which == 0) ? 0.17677669529663687f : 1.0f;
    int tx = threadIdx.x & 15, ty = threadIdx.x >> 4;
    int col = n0 + tx * 4;
    int h = col >> 5, d = col & 31;
    #pragma unroll
    for (int r = 0; r < 4; r++) {
        int tok = m0 + ty * 4 + r;
        int b = tok >> 9, l = tok & 511;
        float4 o = make_float4(acc[r][0] * scale, acc[r][1] * scale,
                               acc[r][2] * scale, acc[r][3] * scale);
        *(float4*)&O[(((b << 3) + h) * SEQ + l) * DKV + d] = o;
    }
}

// ---------------- FC + residual: out = ao @ w_fc + xn ----------------
// grid (32, 4), block 256
__global__ __launch_bounds__(256) void fc_kernel(
        const float* __restrict__ ao, const float* __restrict__ wfc,
        const float* __restrict__ xn, float* __restrict__ out) {
    int m0 = blockIdx.x * 64, n0 = blockIdx.y * 64;
    float acc[4][4] = {};
    gemm_tile_64(ao, wfc, m0, n0, IND, acc);
    int tx = threadIdx.x & 15, ty = threadIdx.x >> 4;
    #pragma unroll
    for (int r = 0; r < 4; r++) {
        int row = m0 + ty * 4 + r;
        float4 xr = *(const float4*)&xn[row * IND + n0 + tx * 4];
        float4 o = make_float4(acc[r][0] + xr.x, acc[r][1] + xr.y,
                               acc[r][2] + xr.z, acc[r][3] + xr.w);
        *(float4*)&out[row * IND + n0 + tx * 4] = o;
    }
}

// ---------------- Attention: L1-distance scores + softmax + PV + am ----------
// grid: (SEQ/16, BH); block: 256   (unchanged from round 1)
__global__ void attn_kernel(const float* __restrict__ Q,
                            const float* __restrict__ Km,
                            const float* __restrict__ V,
                            float* __restrict__ attn_out,  // [tok][256]
                            float* __restrict__ am) {      // [b][512]
    __shared__ __align__(16) float S[16][516];
    __shared__ __align__(16) float T[128][36];

    int gy = blockIdx.y;                  // bh
    int i0 = blockIdx.x * 16;
    int t = threadIdx.x;
    int b = gy >> 3, h = gy & 7;
    const float* Qb = Q + gy * SEQ * DKV;
    const float* Kb = Km + gy * SEQ * DKV;
    const float* Vb = V + gy * SEQ * DKV;

    int ti = t >> 4;     // i in 0..15
    int tj = t & 15;     // j sub-lane

    float4 kreg[8];
    #pragma unroll
    for (int c = 0; c < 8; c++)
        kreg[c] = *(const float4*)&Kb[(i0 + ti) * DKV + c * 4];

    // ---- Phase 1: S[i][j] = mean_d |q_j[d] - k_i[d]| ----
    for (int jt = 0; jt < 4; jt++) {
        #pragma unroll
        for (int n = 0; n < 4; n++) {
            int cidx = t + n * 256;
            int row = cidx >> 3, ch = cidx & 7;
            *(float4*)&T[row][ch * 4] =
                *(const float4*)&Qb[(jt * 128 + row) * DKV + ch * 4];
        }
        __syncthreads();
        #pragma unroll
        for (int m = 0; m < 8; m++) {
            int jl = tj + m * 16;
            float acc = 0.0f;
            #pragma unroll
            for (int c = 0; c < 8; c++) {
                float4 qv = *(const float4*)&T[jl][c * 4];
                acc += fabsf(qv.x - kreg[c].x) + fabsf(qv.y - kreg[c].y)
                     + fabsf(qv.z - kreg[c].z) + fabsf(qv.w - kreg[c].w);
            }
            S[ti][jt * 128 + jl] = acc * (1.0f / 32.0f);
        }
        __syncthreads();
    }

    // ---- Phase 2: row softmax ----
    float vals[32];
    float mx = -1e30f;
    #pragma unroll
    for (int m = 0; m < 32; m++) {
        vals[m] = S[ti][tj + m * 16];
        mx = fmaxf(mx, vals[m]);
    }
    #pragma unroll
    for (int o = 1; o < 16; o <<= 1) mx = fmaxf(mx, __shfl_xor(mx, o, 64));
    float sum = 0.0f;
    #pragma unroll
    for (int m = 0; m < 32; m++) {
        vals[m] = expf(vals[m] - mx);
        sum += vals[m];
    }
    #pragma unroll
    for (int o = 1; o < 16; o <<= 1) sum += __shfl_xor(sum, o, 64);
    float inv = 1.0f / sum;
    #pragma unroll
    for (int m = 0; m < 32; m++) S[ti][tj + m * 16] = vals[m] * inv;
    __syncthreads();

    // ---- am partial ----
    #pragma unroll
    for (int n = 0; n < 2; n++) {
        int j = t + n * 256;
        float cs = 0.0f;
        #pragma unroll
        for (int i = 0; i < 16; i++) cs += S[i][j];
        atomicAdd(&am[b * SEQ + j], cs * 0.125f);
    }

    // ---- Phase 3: O[d,i] = sum_j P[i,j] * V[d,j] ----
    int jg = t >> 5;
    int u = t & 31;
    int i4 = (u >> 3) * 4;
    int d4 = (u & 7) * 4;
    float acc3[4][4];
    #pragma unroll
    for (int r = 0; r < 4; r++)
        #pragma unroll
        for (int c = 0; c < 4; c++) acc3[r][c] = 0.0f;

    for (int jt = 0; jt < 4; jt++) {
        #pragma unroll
        for (int n = 0; n < 4; n++) {
            int cidx = t + n * 256;
            int row = cidx >> 3, ch = cidx & 7;
            *(float4*)&T[row][ch * 4] =
                *(const float4*)&Vb[(jt * 128 + row) * DKV + ch * 4];
        }
        __syncthreads();
        #pragma unroll
        for (int n = 0; n < 16; n++) {
            int jl = jg * 16 + n;
            int j = jt * 128 + jl;
            float p0 = S[i4 + 0][j];
            float p1 = S[i4 + 1][j];
            float p2 = S[i4 + 2][j];
            float p3 = S[i4 + 3][j];
            float4 vv = *(const float4*)&T[jl][d4];
            acc3[0][0] = fmaf(p0, vv.x, acc3[0][0]);
            acc3[0][1] = fmaf(p0, vv.y, acc3[0][1]);
            acc3[0][2] = fmaf(p0, vv.z, acc3[0][2]);
            acc3[0][3] = fmaf(p0, vv.w, acc3[0][3]);
            acc3[1][0] = fmaf(p1, vv.x, acc3[1][0]);
            acc3[1][1] = fmaf(p1, vv.y, acc3[1][1]);
            acc3[1][2] = fmaf(p1, vv.z, acc3[1][2]);
            acc3[1][3] = fmaf(p1, vv.w, acc3[1][3]);
            acc3[2][0] = fmaf(p2, vv.x, acc3[2][0]);
            acc3[2][1] = fmaf(p2, vv.y, acc3[2][1]);
            acc3[2][2] = fmaf(p2, vv.z, acc3[2][2]);
            acc3[2][3] = fmaf(p2, vv.w, acc3[2][3]);
            acc3[3][0] = fmaf(p3, vv.x, acc3[3][0]);
            acc3[3][1] = fmaf(p3, vv.y, acc3[3][1]);
            acc3[3][2] = fmaf(p3, vv.z, acc3[3][2]);
            acc3[3][3] = fmaf(p3, vv.w, acc3[3][3]);
        }
        __syncthreads();
    }

    float* Sf = &S[0][0];
    #pragma unroll
    for (int r = 0; r < 4; r++)
        #pragma unroll
        for (int c = 0; c < 4; c++)
            Sf[jg * 512 + (i4 + r) * 32 + d4 + c] = acc3[r][c];
    __syncthreads();
    #pragma unroll
    for (int n = 0; n < 2; n++) {
        int o = t + n * 256;
        int ii = o >> 5, d = o & 31;
        float sm = 0.0f;
        #pragma unroll
        for (int g = 0; g < 8; g++) sm += Sf[g * 512 + o];
        attn_out[(b * SEQ + i0 + ii) * IND + h * 32 + d] = sm;
    }
}

// ---------------- am min-max normalize ----------------
__global__ void amnorm_kernel(const float* __restrict__ am,
                              float* __restrict__ out_am) {
    int b = blockIdx.x;
    int t = threadIdx.x;
    float v0 = am[b * SEQ + t];
    float v1 = am[b * SEQ + t + 256];
    float mn = fminf(v0, v1), mx = fmaxf(v0, v1);
    #pragma unroll
    for (int o = 32; o > 0; o >>= 1) {
        mn = fminf(mn, __shfl_xor(mn, o, 64));
        mx = fmaxf(mx, __shfl_xor(mx, o, 64));
    }
    __shared__ float lmn[4], lmx[4];
    int w = t >> 6;
    if ((t & 63) == 0) { lmn[w] = mn; lmx[w] = mx; }
    __syncthreads();
    mn = fminf(fminf(lmn[0], lmn[1]), fminf(lmn[2], lmn[3]));
    mx = fmaxf(fmaxf(lmx[0], lmx[1]), fmaxf(lmx[2], lmx[3]));
    float inv = 1.0f / (mx - mn);
    out_am[b * SEQ + t]       = (v0 - mn) * inv;
    out_am[b * SEQ + t + 256] = (v1 - mn) * inv;
}

extern "C" void kernel_launch(void* const* d_in, const int* in_sizes, int n_in,
                              void* d_out, int out_size, void* d_ws, size_t ws_size,
                              hipStream_t stream) {
    (void)in_sizes; (void)n_in; (void)out_size; (void)ws_size;
    const float* x     = (const float*)d_in[0];
    const float* w_q   = (const float*)d_in[1];
    const float* w_k   = (const float*)d_in[2];
    const float* w_v   = (const float*)d_in[3];
    const float* w_fc  = (const float*)d_in[4];
    const float* gamma = (const float*)d_in[5];
    const float* beta  = (const float*)d_in[6];
    float* out = (float*)d_out;

    float* ws = (float*)d_ws;
    float* xn = ws;                          // 2048*256
    float* Qw = xn + NTOK * IND;             // 32*512*32
    float* Kw = Qw + BH * SEQ * DKV;
    float* Vw = Kw + BH * SEQ * DKV;
    float* AO = Vw + BH * SEQ * DKV;         // 2048*256
    float* AM = AO + NTOK * IND;             // 4*512

    hipLaunchKernelGGL(zero_am_kernel, dim3(8), dim3(256), 0, stream, AM);
    hipLaunchKernelGGL(ln_kernel, dim3(NTOK), dim3(256), 0, stream, x, gamma, beta, xn);
    hipLaunchKernelGGL(proj_kernel, dim3(32, 4, 3), dim3(256), 0, stream,
                       xn, w_q, w_k, w_v, Qw, Kw, Vw);
    hipLaunchKernelGGL(attn_kernel, dim3(SEQ / 16, BH), dim3(256), 0, stream,
                       Qw, Kw, Vw, AO, AM);
    hipLaunchKernelGGL(fc_kernel, dim3(32, 4), dim3(256), 0, stream,
                       AO, w_fc, xn, out);
    hipLaunchKernelGGL(amnorm_kernel, dim3(BATCH), dim3(256), 0, stream,
                       AM, out + NTOK * IND);
}

// Round 3
// 76.708 us; speedup vs baseline: 2.6607x; 1.2919x over previous
//
#include <hip/hip_runtime.h>
#include <hip/hip_fp16.h>
#include <math.h>

#define BATCH 4
#define SEQ   512
#define IND   256
#define NH    8
#define DKV   32
#define BH    32   // BATCH*NH
#define NTOK  2048 // BATCH*SEQ

__device__ __forceinline__ __half2 habs2_(__half2 x) {
    unsigned u = __builtin_bit_cast(unsigned, x) & 0x7fff7fffu;
    return __builtin_bit_cast(__half2, u);
}
__device__ __forceinline__ __half2 shfl_xor_h2(__half2 x, int m) {
    float f = __builtin_bit_cast(float, x);
    f = __shfl_xor(f, m, 64);
    return __builtin_bit_cast(__half2, f);
}

// ---------------- LayerNorm (+ am zero) ----------------
__global__ void ln_kernel(const float* __restrict__ x,
                          const float* __restrict__ gamma,
                          const float* __restrict__ beta,
                          float* __restrict__ xn,
                          float* __restrict__ am) {
    int row = blockIdx.x;
    int t = threadIdx.x;
    if (blockIdx.x < 8) am[blockIdx.x * 256 + t] = 0.0f;
    float v = x[row * IND + t];
    float s = v, s2 = v * v;
    #pragma unroll
    for (int o = 32; o > 0; o >>= 1) {
        s  += __shfl_xor(s,  o, 64);
        s2 += __shfl_xor(s2, o, 64);
    }
    __shared__ float ls[4], ls2[4];
    int w = t >> 6;
    if ((t & 63) == 0) { ls[w] = s; ls2[w] = s2; }
    __syncthreads();
    s  = ls[0] + ls[1] + ls[2] + ls[3];
    s2 = ls2[0] + ls2[1] + ls2[2] + ls2[3];
    float mu  = s * (1.0f / IND);
    float var = s2 * (1.0f / IND) - mu * mu;
    float r = rsqrtf(var + 1e-6f);
    xn[row * IND + t] = (v - mu) * r * gamma[t] + beta[t];
}

// ---------------- 64x64 tiled fp32 GEMM core (K=256, BK=32, double-buffered) ----
__device__ __forceinline__ void gemm_tile_64(const float* __restrict__ A,
                                             const float* __restrict__ B,
                                             int m0, int n0, int ldb,
                                             float acc[4][4]) {
    __shared__ __align__(16) float As[2][32][68];
    __shared__ __align__(16) float Bs[2][32][68];
    const int t  = threadIdx.x;
    const int tx = t & 15, ty = t >> 4;
    const int am = t >> 3, ac = (t & 7) * 4;
    const int bk = t >> 4, bn = (t & 15) * 4;

    float4 a0, a1, b0, b1;
    auto loadG = [&](int kc) {
        a0 = *(const float4*)&A[(m0 + am) * IND + kc * 32 + ac];
        a1 = *(const float4*)&A[(m0 + 32 + am) * IND + kc * 32 + ac];
        b0 = *(const float4*)&B[(kc * 32 + bk) * ldb + n0 + bn];
        b1 = *(const float4*)&B[(kc * 32 + 16 + bk) * ldb + n0 + bn];
    };
    auto storeL = [&](int buf) {
        As[buf][ac + 0][am] = a0.x; As[buf][ac + 1][am] = a0.y;
        As[buf][ac + 2][am] = a0.z; As[buf][ac + 3][am] = a0.w;
        As[buf][ac + 0][am + 32] = a1.x; As[buf][ac + 1][am + 32] = a1.y;
        As[buf][ac + 2][am + 32] = a1.z; As[buf][ac + 3][am + 32] = a1.w;
        *(float4*)&Bs[buf][bk][bn]      = b0;
        *(float4*)&Bs[buf][16 + bk][bn] = b1;
    };

    loadG(0); storeL(0);
    for (int kc = 0; kc < 8; kc++) {
        __syncthreads();
        if (kc < 7) loadG(kc + 1);
        const int buf = kc & 1;
        #pragma unroll
        for (int kk = 0; kk < 32; kk++) {
            float4 av = *(const float4*)&As[buf][kk][ty * 4];
            float4 bv = *(const float4*)&Bs[buf][kk][tx * 4];
            acc[0][0] = fmaf(av.x, bv.x, acc[0][0]);
            acc[0][1] = fmaf(av.x, bv.y, acc[0][1]);
            acc[0][2] = fmaf(av.x, bv.z, acc[0][2]);
            acc[0][3] = fmaf(av.x, bv.w, acc[0][3]);
            acc[1][0] = fmaf(av.y, bv.x, acc[1][0]);
            acc[1][1] = fmaf(av.y, bv.y, acc[1][1]);
            acc[1][2] = fmaf(av.y, bv.z, acc[1][2]);
            acc[1][3] = fmaf(av.y, bv.w, acc[1][3]);
            acc[2][0] = fmaf(av.z, bv.x, acc[2][0]);
            acc[2][1] = fmaf(av.z, bv.y, acc[2][1]);
            acc[2][2] = fmaf(av.z, bv.z, acc[2][2]);
            acc[2][3] = fmaf(av.z, bv.w, acc[2][3]);
            acc[3][0] = fmaf(av.w, bv.x, acc[3][0]);
            acc[3][1] = fmaf(av.w, bv.y, acc[3][1]);
            acc[3][2] = fmaf(av.w, bv.z, acc[3][2]);
            acc[3][3] = fmaf(av.w, bv.w, acc[3][3]);
        }
        if (kc < 7) { __syncthreads(); storeL((kc + 1) & 1); }
    }
}

// ---------------- Projections -> f16 Q,K,V in [bh][l][32] ----------------
__global__ __launch_bounds__(256) void proj_kernel(
        const float* __restrict__ xn,
        const float* __restrict__ wq, const float* __restrict__ wk,
        const float* __restrict__ wv,
        __half* __restrict__ Q, __half* __restrict__ K, __half* __restrict__ V) {
    int which = blockIdx.z;
    const float* W = (which == 0) ? wq : (which == 1) ? wk : wv;
    __half* O = (which == 0) ? Q : (which == 1) ? K : V;
    int m0 = blockIdx.x * 64, n0 = blockIdx.y * 64;
    float acc[4][4] = {};
    gemm_tile_64(xn, W, m0, n0, IND, acc);
    float scale = (which == 0) ? 0.17677669529663687f : 1.0f;
    int tx = threadIdx.x & 15, ty = threadIdx.x >> 4;
    int col = n0 + tx * 4;
    int h = col >> 5, d = col & 31;
    #pragma unroll
    for (int r = 0; r < 4; r++) {
        int tok = m0 + ty * 4 + r;
        int b = tok >> 9, l = tok & 511;
        __half2 p0 = __halves2half2(__float2half_rn(acc[r][0] * scale),
                                    __float2half_rn(acc[r][1] * scale));
        __half2 p1 = __halves2half2(__float2half_rn(acc[r][2] * scale),
                                    __float2half_rn(acc[r][3] * scale));
        __half* dst = O + (((b << 3) + h) * SEQ + l) * DKV + d;
        *(__half2*)dst = p0;
        *(__half2*)(dst + 2) = p1;
    }
}

// ---------------- Attention: f16 packed, scores in registers ----------------
// grid (SEQ/16, BH), block 256. Thread owns rows i0+g and i0+g+8 (g=t>>5),
// j-slice jl=t&31 (j = tile*128 + m*32 + jl, m=0..3 per tile).
__global__ __launch_bounds__(256) void attn_kernel(
        const __half* __restrict__ Qh, const __half* __restrict__ Kh,
        const __half* __restrict__ Vh, float* __restrict__ attn_out,
        float* __restrict__ am) {
    __shared__ __align__(16) __half Th[2][128][40];
    const int t = threadIdx.x;
    const int gy = blockIdx.y;
    const int i0 = blockIdx.x * 16;
    const int b = gy >> 3, h = gy & 7;
    const __half* Qb = Qh + gy * SEQ * DKV;
    const __half* Kb = Kh + gy * SEQ * DKV;
    const __half* Vb = Vh + gy * SEQ * DKV;
    const int g = t >> 5, jl = t & 31;
    const int r0 = t >> 2, ch = t & 3;

    // K rows (i0+g, i0+g+8) in registers as half2
    __half2 ka[16], kb[16];
    {
        const float4* pa = (const float4*)(Kb + (i0 + g) * DKV);
        const float4* pb = (const float4*)(Kb + (i0 + g + 8) * DKV);
        #pragma unroll
        for (int c = 0; c < 4; c++) {
            float4 va = pa[c], vb = pb[c];
            const __half2* ha = (const __half2*)&va;
            const __half2* hb = (const __half2*)&vb;
            #pragma unroll
            for (int k = 0; k < 4; k++) { ka[c*4+k] = ha[k]; kb[c*4+k] = hb[k]; }
        }
    }

    float vals_a[16], vals_b[16];
    float4 pre0, pre1;

    // ---- Phase 1: scores (Q tiles of 128 rows, double-buffered) ----
    pre0 = *(const float4*)(Qb + r0 * DKV + ch * 8);
    pre1 = *(const float4*)(Qb + (r0 + 64) * DKV + ch * 8);
    *(float4*)&Th[0][r0][ch * 8] = pre0;
    *(float4*)&Th[0][r0 + 64][ch * 8] = pre1;
    __syncthreads();
    #pragma unroll
    for (int tile = 0; tile < 4; tile++) {
        const int buf = tile & 1;
        if (tile < 3) {
            pre0 = *(const float4*)(Qb + ((tile+1)*128 + r0) * DKV + ch * 8);
            pre1 = *(const float4*)(Qb + ((tile+1)*128 + r0 + 64) * DKV + ch * 8);
        }
        #pragma unroll
        for (int m = 0; m < 4; m++) {
            const int j = jl + m * 32;
            __half2 z = __float2half2_rn(0.0f);
            __half2 sa0 = z, sa1 = z, sb0 = z, sb1 = z;
            #pragma unroll
            for (int c = 0; c < 4; c++) {
                float4 qv = *(const float4*)&Th[buf][j][c * 8];
                const __half2* q2 = (const __half2*)&qv;
                #pragma unroll
                for (int k = 0; k < 4; k++) {
                    __half2 da = habs2_(__hsub2(q2[k], ka[c*4+k]));
                    __half2 db = habs2_(__hsub2(q2[k], kb[c*4+k]));
                    if (k & 1) { sa1 = __hadd2(sa1, da); sb1 = __hadd2(sb1, db); }
                    else       { sa0 = __hadd2(sa0, da); sb0 = __hadd2(sb0, db); }
                }
            }
            __half2 sa = __hadd2(sa0, sa1), sb = __hadd2(sb0, sb1);
            vals_a[tile*4+m] = (__low2float(sa) + __high2float(sa)) * (1.0f/32.0f);
            vals_b[tile*4+m] = (__low2float(sb) + __high2float(sb)) * (1.0f/32.0f);
        }
        if (tile < 3) {
            *(float4*)&Th[buf ^ 1][r0][ch * 8] = pre0;
            *(float4*)&Th[buf ^ 1][r0 + 64][ch * 8] = pre1;
        }
        __syncthreads();
    }

    // ---- Phase 2: softmax over j (32 lanes per row) ----
    float mxa = vals_a[0], mxb = vals_b[0];
    #pragma unroll
    for (int m = 1; m < 16; m++) {
        mxa = fmaxf(mxa, vals_a[m]); mxb = fmaxf(mxb, vals_b[m]);
    }
    #pragma unroll
    for (int s = 1; s <= 16; s <<= 1) {
        mxa = fmaxf(mxa, __shfl_xor(mxa, s, 64));
        mxb = fmaxf(mxb, __shfl_xor(mxb, s, 64));
    }
    float sua = 0.0f, sub = 0.0f;
    #pragma unroll
    for (int m = 0; m < 16; m++) {
        vals_a[m] = __expf(vals_a[m] - mxa); sua += vals_a[m];
        vals_b[m] = __expf(vals_b[m] - mxb); sub += vals_b[m];
    }
    #pragma unroll
    for (int s = 1; s <= 16; s <<= 1) {
        sua += __shfl_xor(sua, s, 64);
        sub += __shfl_xor(sub, s, 64);
    }
    float inva = 1.0f / sua, invb = 1.0f / sub;
    #pragma unroll
    for (int m = 0; m < 16; m++) { vals_a[m] *= inva; vals_b[m] *= invb; }

    // ---- Phase 3: PV (V tiles of 128 rows, double-buffered, packed hfma2) ----
    __half2 acc_a[16], acc_b[16];
    #pragma unroll
    for (int k = 0; k < 16; k++) {
        acc_a[k] = __float2half2_rn(0.0f);
        acc_b[k] = __float2half2_rn(0.0f);
    }
    pre0 = *(const float4*)(Vb + r0 * DKV + ch * 8);
    pre1 = *(const float4*)(Vb + (r0 + 64) * DKV + ch * 8);
    *(float4*)&Th[0][r0][ch * 8] = pre0;
    *(float4*)&Th[0][r0 + 64][ch * 8] = pre1;
    __syncthreads();
    #pragma unroll
    for (int tile = 0; tile < 4; tile++) {
        const int buf = tile & 1;
        if (tile < 3) {
            pre0 = *(const float4*)(Vb + ((tile+1)*128 + r0) * DKV + ch * 8);
            pre1 = *(const float4*)(Vb + ((tile+1)*128 + r0 + 64) * DKV + ch * 8);
        }
        #pragma unroll
        for (int m = 0; m < 4; m++) {
            const int j = jl + m * 32;
            __half2 pa = __float2half2_rn(vals_a[tile*4+m]);
            __half2 pb = __float2half2_rn(vals_b[tile*4+m]);
            #pragma unroll
            for (int c = 0; c < 4; c++) {
                float4 vv = *(const float4*)&Th[buf][j][c * 8];
                const __half2* v2 = (const __half2*)&vv;
                #pragma unroll
                for (int k = 0; k < 4; k++) {
                    acc_a[c*4+k] = __hfma2(pa, v2[k], acc_a[c*4+k]);
                    acc_b[c*4+k] = __hfma2(pb, v2[k], acc_b[c*4+k]);
                }
            }
        }
        if (tile < 3) {
            *(float4*)&Th[buf ^ 1][r0][ch * 8] = pre0;
            *(float4*)&Th[buf ^ 1][r0 + 64][ch * 8] = pre1;
        }
        __syncthreads();
    }

    // ---- O reduction across 32 j-lanes (butterfly; lane ends with d-pair (jl>>1)&15)
#define REDSTEP(S, C)                                                      \
    {                                                                      \
        _Pragma("unroll")                                                  \
        for (int k = 0; k < (C); k++) {                                    \
            __half2 sa = (jl & (S)) ? acc_a[k] : acc_a[k + (C)];           \
            __half2 sb = (jl & (S)) ? acc_b[k] : acc_b[k + (C)];           \
            __half2 ra = shfl_xor_h2(sa, (S));                             \
            __half2 rb = shfl_xor_h2(sb, (S));                             \
            __half2 qa = (jl & (S)) ? acc_a[k + (C)] : acc_a[k];           \
            __half2 qb = (jl & (S)) ? acc_b[k + (C)] : acc_b[k];           \
            acc_a[k] = __hadd2(qa, ra);                                    \
            acc_b[k] = __hadd2(qb, rb);                                    \
        }                                                                  \
    }
    REDSTEP(16, 8)
    REDSTEP(8, 4)
    REDSTEP(4, 2)
    REDSTEP(2, 1)
#undef REDSTEP
    acc_a[0] = __hadd2(acc_a[0], shfl_xor_h2(acc_a[0], 1));
    acc_b[0] = __hadd2(acc_b[0], shfl_xor_h2(acc_b[0], 1));
    if (!(jl & 1)) {
        int d2 = (jl >> 1) & 15;
        int col = h * 32 + d2 * 2;
        float2 oa = make_float2(__low2float(acc_a[0]), __high2float(acc_a[0]));
        float2 ob = make_float2(__low2float(acc_b[0]), __high2float(acc_b[0]));
        *(float2*)&attn_out[(b * SEQ + i0 + g) * IND + col] = oa;
        *(float2*)&attn_out[(b * SEQ + i0 + g + 8) * IND + col] = ob;
    }

    // ---- am column sums (P col partials -> LDS across waves -> global atomic)
    float colp[16];
    #pragma unroll
    for (int m = 0; m < 16; m++) {
        float cp = vals_a[m] + vals_b[m];
        cp += __shfl_xor(cp, 32, 64);
        colp[m] = cp;
    }
    float* amw = (float*)&Th[0][0][0];
    const int w = t >> 6;
    if (!(t & 32)) {
        #pragma unroll
        for (int m = 0; m < 16; m++) {
            int j = (m >> 2) * 128 + (m & 3) * 32 + jl;
            amw[w * 512 + j] = colp[m];
        }
    }
    __syncthreads();
    #pragma unroll
    for (int n = 0; n < 2; n++) {
        int j = t + n * 256;
        float s = (amw[j] + amw[512 + j] + amw[1024 + j] + amw[1536 + j]) * 0.125f;
        atomicAdd(&am[b * SEQ + j], s);
    }
}

// ---------------- FC + residual: out = ao @ w_fc + xn ----------------
__global__ __launch_bounds__(256) void fc_kernel(
        const float* __restrict__ ao, const float* __restrict__ wfc,
        const float* __restrict__ xn, float* __restrict__ out) {
    int m0 = blockIdx.x * 64, n0 = blockIdx.y * 64;
    float acc[4][4] = {};
    gemm_tile_64(ao, wfc, m0, n0, IND, acc);
    int tx = threadIdx.x & 15, ty = threadIdx.x >> 4;
    #pragma unroll
    for (int r = 0; r < 4; r++) {
        int row = m0 + ty * 4 + r;
        float4 xr = *(const float4*)&xn[row * IND + n0 + tx * 4];
        float4 o = make_float4(acc[r][0] + xr.x, acc[r][1] + xr.y,
                               acc[r][2] + xr.z, acc[r][3] + xr.w);
        *(float4*)&out[row * IND + n0 + tx * 4] = o;
    }
}

// ---------------- am min-max normalize ----------------
__global__ void amnorm_kernel(const float* __restrict__ am,
                              float* __restrict__ out_am) {
    int b = blockIdx.x;
    int t = threadIdx.x;
    float v0 = am[b * SEQ + t];
    float v1 = am[b * SEQ + t + 256];
    float mn = fminf(v0, v1), mx = fmaxf(v0, v1);
    #pragma unroll
    for (int o = 32; o > 0; o >>= 1) {
        mn = fminf(mn, __shfl_xor(mn, o, 64));
        mx = fmaxf(mx, __shfl_xor(mx, o, 64));
    }
    __shared__ float lmn[4], lmx[4];
    int w = t >> 6;
    if ((t & 63) == 0) { lmn[w] = mn; lmx[w] = mx; }
    __syncthreads();
    mn = fminf(fminf(lmn[0], lmn[1]), fminf(lmn[2], lmn[3]));
    mx = fmaxf(fmaxf(lmx[0], lmx[1]), fmaxf(lmx[2], lmx[3]));
    float inv = 1.0f / (mx - mn);
    out_am[b * SEQ + t]       = (v0 - mn) * inv;
    out_am[b * SEQ + t + 256] = (v1 - mn) * inv;
}

extern "C" void kernel_launch(void* const* d_in, const int* in_sizes, int n_in,
                              void* d_out, int out_size, void* d_ws, size_t ws_size,
                              hipStream_t stream) {
    (void)in_sizes; (void)n_in; (void)out_size; (void)ws_size;
    const float* x     = (const float*)d_in[0];
    const float* w_q   = (const float*)d_in[1];
    const float* w_k   = (const float*)d_in[2];
    const float* w_v   = (const float*)d_in[3];
    const float* w_fc  = (const float*)d_in[4];
    const float* gamma = (const float*)d_in[5];
    const float* beta  = (const float*)d_in[6];
    float* out = (float*)d_out;

    float* ws = (float*)d_ws;
    float* xn = ws;                          // 2048*256 f32
    float* AO = xn + NTOK * IND;             // 2048*256 f32
    float* AM = AO + NTOK * IND;             // 2048 f32
    __half* Qh = (__half*)(AM + NTOK);       // 32*512*32 f16 each
    __half* Kh = Qh + BH * SEQ * DKV;
    __half* Vh = Kh + BH * SEQ * DKV;

    hipLaunchKernelGGL(ln_kernel, dim3(NTOK), dim3(256), 0, stream,
                       x, gamma, beta, xn, AM);
    hipLaunchKernelGGL(proj_kernel, dim3(32, 4, 3), dim3(256), 0, stream,
                       xn, w_q, w_k, w_v, Qh, Kh, Vh);
    hipLaunchKernelGGL(attn_kernel, dim3(SEQ / 16, BH), dim3(256), 0, stream,
                       Qh, Kh, Vh, AO, AM);
    hipLaunchKernelGGL(fc_kernel, dim3(32, 4), dim3(256), 0, stream,
                       AO, w_fc, xn, out);
    hipLaunchKernelGGL(amnorm_kernel, dim3(BATCH), dim3(256), 0, stream,
                       AM, out + NTOK * IND);
}

// Round 4
// 67.719 us; speedup vs baseline: 3.0139x; 1.1327x over previous
//
#include <hip/hip_runtime.h>
#include <hip/hip_fp16.h>
#include <math.h>

#define BATCH 4
#define SEQ   512
#define IND   256
#define NH    8
#define DKV   32
#define BH    32   // BATCH*NH
#define NTOK  2048 // BATCH*SEQ

typedef __attribute__((ext_vector_type(8))) short short8v;
typedef __attribute__((ext_vector_type(4))) float floatx4;

__device__ __forceinline__ unsigned f2bf1(float f) {
    unsigned u = __builtin_bit_cast(unsigned, f);
    return (u + 0x7fffu + ((u >> 16) & 1u)) >> 16;
}
__device__ __forceinline__ unsigned f2bf2(float lo, float hi) {
    return f2bf1(lo) | (f2bf1(hi) << 16);
}
__device__ __forceinline__ __half2 habs2_(__half2 x) {
    unsigned u = __builtin_bit_cast(unsigned, x) & 0x7fff7fffu;
    return __builtin_bit_cast(__half2, u);
}
__device__ __forceinline__ __half2 shfl_xor_h2(__half2 x, int m) {
    float f = __builtin_bit_cast(float, x);
    f = __shfl_xor(f, m, 64);
    return __builtin_bit_cast(__half2, f);
}

// ============ Kernel 1: fused LayerNorm + Q/K/V projections (bf16 MFMA) =====
// grid (32, 12): x = 64-row tile, y: which = y>>2 (0=q,1=k,2=v), n0 = (y&3)*64
__global__ __launch_bounds__(256) void lnproj_kernel(
        const float* __restrict__ x,
        const float* __restrict__ gamma, const float* __restrict__ beta,
        const float* __restrict__ wq, const float* __restrict__ wk,
        const float* __restrict__ wv,
        float* __restrict__ xn, float* __restrict__ am,
        __half* __restrict__ Q, __half* __restrict__ K, __half* __restrict__ V) {
    __shared__ __align__(16) unsigned short As[64][264];   // [m][k] bf16, full K
    __shared__ __align__(16) unsigned short Bs[2][64][40]; // [n][k] bf16, K-tile 32
    const int t = threadIdx.x;
    const int m0 = blockIdx.x * 64;
    const int y = blockIdx.y;
    const int which = y >> 2;
    const int n0 = (y & 3) * 64;
    const float* W = (which == 0) ? wq : (which == 1) ? wk : wv;
    __half* O = (which == 0) ? Q : (which == 1) ? K : V;

    // ---- Phase A: LayerNorm rows m0..m0+63 -> As (bf16) ----
    {
        const int r = t >> 2, q = t & 3;
        const float* xr = x + (m0 + r) * IND + q * 64;
        float4 xv[16];
        float s = 0.0f, s2 = 0.0f;
        #pragma unroll
        for (int i = 0; i < 16; i++) {
            xv[i] = *(const float4*)&xr[i * 4];
            s  += xv[i].x + xv[i].y + xv[i].z + xv[i].w;
            s2 += xv[i].x * xv[i].x + xv[i].y * xv[i].y
                + xv[i].z * xv[i].z + xv[i].w * xv[i].w;
        }
        s  += __shfl_xor(s, 1, 64);  s  += __shfl_xor(s, 2, 64);
        s2 += __shfl_xor(s2, 1, 64); s2 += __shfl_xor(s2, 2, 64);
        float mu = s * (1.0f / IND);
        float var = s2 * (1.0f / IND) - mu * mu;
        float rinv = rsqrtf(var + 1e-6f);
        const bool dox = (y == 0);
        if (dox && t < 64) am[m0 + t] = 0.0f;
        #pragma unroll
        for (int i = 0; i < 8; i++) {
            float4 a = xv[2 * i], bv = xv[2 * i + 1];
            float4 g0 = *(const float4*)&gamma[q * 64 + i * 8];
            float4 g1 = *(const float4*)&gamma[q * 64 + i * 8 + 4];
            float4 b0 = *(const float4*)&beta[q * 64 + i * 8];
            float4 b1 = *(const float4*)&beta[q * 64 + i * 8 + 4];
            float4 n0v, n1v;
            n0v.x = (a.x - mu) * rinv * g0.x + b0.x;
            n0v.y = (a.y - mu) * rinv * g0.y + b0.y;
            n0v.z = (a.z - mu) * rinv * g0.z + b0.z;
            n0v.w = (a.w - mu) * rinv * g0.w + b0.w;
            n1v.x = (bv.x - mu) * rinv * g1.x + b1.x;
            n1v.y = (bv.y - mu) * rinv * g1.y + b1.y;
            n1v.z = (bv.z - mu) * rinv * g1.z + b1.z;
            n1v.w = (bv.w - mu) * rinv * g1.w + b1.w;
            if (dox) {
                *(float4*)&xn[(m0 + r) * IND + q * 64 + i * 8] = n0v;
                *(float4*)&xn[(m0 + r) * IND + q * 64 + i * 8 + 4] = n1v;
            }
            uint4 pk;
            pk.x = f2bf2(n0v.x, n0v.y); pk.y = f2bf2(n0v.z, n0v.w);
            pk.z = f2bf2(n1v.x, n1v.y); pk.w = f2bf2(n1v.z, n1v.w);
            *(uint4*)&As[r][q * 64 + i * 8] = pk;
        }
    }

    // ---- Phase B: MFMA over K (B double-buffered per 32-k tile) ----
    const int w = t >> 6, l = t & 63;
    const int wm = (w >> 1) * 32, wn = (w & 1) * 32;
    const int fr = l & 15, fg = l >> 4;
    floatx4 acc[2][2];
    #pragma unroll
    for (int i = 0; i < 2; i++)
        #pragma unroll
        for (int j = 0; j < 2; j++) acc[i][j] = (floatx4)(0.0f);

    const int kl = t >> 4, nq = t & 15;
    auto stageB = [&](int kt, int buf) {
        float4 b0 = *(const float4*)&W[(kt * 32 + kl) * IND + n0 + nq * 4];
        float4 b1 = *(const float4*)&W[(kt * 32 + 16 + kl) * IND + n0 + nq * 4];
        Bs[buf][nq * 4 + 0][kl] = (unsigned short)f2bf1(b0.x);
        Bs[buf][nq * 4 + 1][kl] = (unsigned short)f2bf1(b0.y);
        Bs[buf][nq * 4 + 2][kl] = (unsigned short)f2bf1(b0.z);
        Bs[buf][nq * 4 + 3][kl] = (unsigned short)f2bf1(b0.w);
        Bs[buf][nq * 4 + 0][kl + 16] = (unsigned short)f2bf1(b1.x);
        Bs[buf][nq * 4 + 1][kl + 16] = (unsigned short)f2bf1(b1.y);
        Bs[buf][nq * 4 + 2][kl + 16] = (unsigned short)f2bf1(b1.z);
        Bs[buf][nq * 4 + 3][kl + 16] = (unsigned short)f2bf1(b1.w);
    };
    stageB(0, 0);
    __syncthreads();
    #pragma unroll
    for (int kt = 0; kt < 8; kt++) {
        if (kt < 7) stageB(kt + 1, (kt + 1) & 1);
        const int buf = kt & 1;
        short8v a0 = *(const short8v*)&As[wm + fr][kt * 32 + fg * 8];
        short8v a1 = *(const short8v*)&As[wm + 16 + fr][kt * 32 + fg * 8];
        short8v b0 = *(const short8v*)&Bs[buf][wn + fr][fg * 8];
        short8v b1 = *(const short8v*)&Bs[buf][wn + 16 + fr][fg * 8];
        acc[0][0] = __builtin_amdgcn_mfma_f32_16x16x32_bf16(a0, b0, acc[0][0], 0, 0, 0);
        acc[0][1] = __builtin_amdgcn_mfma_f32_16x16x32_bf16(a0, b1, acc[0][1], 0, 0, 0);
        acc[1][0] = __builtin_amdgcn_mfma_f32_16x16x32_bf16(a1, b0, acc[1][0], 0, 0, 0);
        acc[1][1] = __builtin_amdgcn_mfma_f32_16x16x32_bf16(a1, b1, acc[1][1], 0, 0, 0);
        __syncthreads();
    }

    // ---- Epilogue: scale (q only), f16 store to [bh][l][32] ----
    const float scale = (which == 0) ? 0.17677669529663687f : 1.0f;
    #pragma unroll
    for (int mi = 0; mi < 2; mi++)
        #pragma unroll
        for (int ni = 0; ni < 2; ni++)
            #pragma unroll
            for (int reg = 0; reg < 4; reg++) {
                int row = m0 + wm + mi * 16 + fg * 4 + reg;   // token
                int col = n0 + wn + ni * 16 + fr;             // 0..255
                int b = row >> 9, ll = row & 511;
                int h = col >> 5, d = col & 31;
                O[(((b << 3) + h) * SEQ + ll) * DKV + d] =
                    __float2half_rn(acc[mi][ni][reg] * scale);
            }
}

// ============ Kernel 2: attention (unchanged from round 3) ==================
__global__ __launch_bounds__(256) void attn_kernel(
        const __half* __restrict__ Qh, const __half* __restrict__ Kh,
        const __half* __restrict__ Vh, float* __restrict__ attn_out,
        float* __restrict__ am) {
    __shared__ __align__(16) __half Th[2][128][40];
    const int t = threadIdx.x;
    const int gy = blockIdx.y;
    const int i0 = blockIdx.x * 16;
    const int b = gy >> 3, h = gy & 7;
    const __half* Qb = Qh + gy * SEQ * DKV;
    const __half* Kb = Kh + gy * SEQ * DKV;
    const __half* Vb = Vh + gy * SEQ * DKV;
    const int g = t >> 5, jl = t & 31;
    const int r0 = t >> 2, ch = t & 3;

    __half2 ka[16], kb[16];
    {
        const float4* pa = (const float4*)(Kb + (i0 + g) * DKV);
        const float4* pb = (const float4*)(Kb + (i0 + g + 8) * DKV);
        #pragma unroll
        for (int c = 0; c < 4; c++) {
            float4 va = pa[c], vb = pb[c];
            const __half2* ha = (const __half2*)&va;
            const __half2* hb = (const __half2*)&vb;
            #pragma unroll
            for (int k = 0; k < 4; k++) { ka[c*4+k] = ha[k]; kb[c*4+k] = hb[k]; }
        }
    }

    float vals_a[16], vals_b[16];
    float4 pre0, pre1;

    pre0 = *(const float4*)(Qb + r0 * DKV + ch * 8);
    pre1 = *(const float4*)(Qb + (r0 + 64) * DKV + ch * 8);
    *(float4*)&Th[0][r0][ch * 8] = pre0;
    *(float4*)&Th[0][r0 + 64][ch * 8] = pre1;
    __syncthreads();
    #pragma unroll
    for (int tile = 0; tile < 4; tile++) {
        const int buf = tile & 1;
        if (tile < 3) {
            pre0 = *(const float4*)(Qb + ((tile+1)*128 + r0) * DKV + ch * 8);
            pre1 = *(const float4*)(Qb + ((tile+1)*128 + r0 + 64) * DKV + ch * 8);
        }
        #pragma unroll
        for (int m = 0; m < 4; m++) {
            const int j = jl + m * 32;
            __half2 z = __float2half2_rn(0.0f);
            __half2 sa0 = z, sa1 = z, sb0 = z, sb1 = z;
            #pragma unroll
            for (int c = 0; c < 4; c++) {
                float4 qv = *(const float4*)&Th[buf][j][c * 8];
                const __half2* q2 = (const __half2*)&qv;
                #pragma unroll
                for (int k = 0; k < 4; k++) {
                    __half2 da = habs2_(__hsub2(q2[k], ka[c*4+k]));
                    __half2 db = habs2_(__hsub2(q2[k], kb[c*4+k]));
                    if (k & 1) { sa1 = __hadd2(sa1, da); sb1 = __hadd2(sb1, db); }
                    else       { sa0 = __hadd2(sa0, da); sb0 = __hadd2(sb0, db); }
                }
            }
            __half2 sa = __hadd2(sa0, sa1), sb = __hadd2(sb0, sb1);
            vals_a[tile*4+m] = (__low2float(sa) + __high2float(sa)) * (1.0f/32.0f);
            vals_b[tile*4+m] = (__low2float(sb) + __high2float(sb)) * (1.0f/32.0f);
        }
        if (tile < 3) {
            *(float4*)&Th[buf ^ 1][r0][ch * 8] = pre0;
            *(float4*)&Th[buf ^ 1][r0 + 64][ch * 8] = pre1;
        }
        __syncthreads();
    }

    float mxa = vals_a[0], mxb = vals_b[0];
    #pragma unroll
    for (int m = 1; m < 16; m++) {
        mxa = fmaxf(mxa, vals_a[m]); mxb = fmaxf(mxb, vals_b[m]);
    }
    #pragma unroll
    for (int s = 1; s <= 16; s <<= 1) {
        mxa = fmaxf(mxa, __shfl_xor(mxa, s, 64));
        mxb = fmaxf(mxb, __shfl_xor(mxb, s, 64));
    }
    float sua = 0.0f, sub = 0.0f;
    #pragma unroll
    for (int m = 0; m < 16; m++) {
        vals_a[m] = __expf(vals_a[m] - mxa); sua += vals_a[m];
        vals_b[m] = __expf(vals_b[m] - mxb); sub += vals_b[m];
    }
    #pragma unroll
    for (int s = 1; s <= 16; s <<= 1) {
        sua += __shfl_xor(sua, s, 64);
        sub += __shfl_xor(sub, s, 64);
    }
    float inva = 1.0f / sua, invb = 1.0f / sub;
    #pragma unroll
    for (int m = 0; m < 16; m++) { vals_a[m] *= inva; vals_b[m] *= invb; }

    __half2 acc_a[16], acc_b[16];
    #pragma unroll
    for (int k = 0; k < 16; k++) {
        acc_a[k] = __float2half2_rn(0.0f);
        acc_b[k] = __float2half2_rn(0.0f);
    }
    pre0 = *(const float4*)(Vb + r0 * DKV + ch * 8);
    pre1 = *(const float4*)(Vb + (r0 + 64) * DKV + ch * 8);
    *(float4*)&Th[0][r0][ch * 8] = pre0;
    *(float4*)&Th[0][r0 + 64][ch * 8] = pre1;
    __syncthreads();
    #pragma unroll
    for (int tile = 0; tile < 4; tile++) {
        const int buf = tile & 1;
        if (tile < 3) {
            pre0 = *(const float4*)(Vb + ((tile+1)*128 + r0) * DKV + ch * 8);
            pre1 = *(const float4*)(Vb + ((tile+1)*128 + r0 + 64) * DKV + ch * 8);
        }
        #pragma unroll
        for (int m = 0; m < 4; m++) {
            const int j = jl + m * 32;
            __half2 pa = __float2half2_rn(vals_a[tile*4+m]);
            __half2 pb = __float2half2_rn(vals_b[tile*4+m]);
            #pragma unroll
            for (int c = 0; c < 4; c++) {
                float4 vv = *(const float4*)&Th[buf][j][c * 8];
                const __half2* v2 = (const __half2*)&vv;
                #pragma unroll
                for (int k = 0; k < 4; k++) {
                    acc_a[c*4+k] = __hfma2(pa, v2[k], acc_a[c*4+k]);
                    acc_b[c*4+k] = __hfma2(pb, v2[k], acc_b[c*4+k]);
                }
            }
        }
        if (tile < 3) {
            *(float4*)&Th[buf ^ 1][r0][ch * 8] = pre0;
            *(float4*)&Th[buf ^ 1][r0 + 64][ch * 8] = pre1;
        }
        __syncthreads();
    }

#define REDSTEP(S, C)                                                      \
    {                                                                      \
        _Pragma("unroll")                                                  \
        for (int k = 0; k < (C); k++) {                                    \
            __half2 sa = (jl & (S)) ? acc_a[k] : acc_a[k + (C)];           \
            __half2 sb = (jl & (S)) ? acc_b[k] : acc_b[k + (C)];           \
            __half2 ra = shfl_xor_h2(sa, (S));                             \
            __half2 rb = shfl_xor_h2(sb, (S));                             \
            __half2 qa = (jl & (S)) ? acc_a[k + (C)] : acc_a[k];           \
            __half2 qb = (jl & (S)) ? acc_b[k + (C)] : acc_b[k];           \
            acc_a[k] = __hadd2(qa, ra);                                    \
            acc_b[k] = __hadd2(qb, rb);                                    \
        }                                                                  \
    }
    REDSTEP(16, 8)
    REDSTEP(8, 4)
    REDSTEP(4, 2)
    REDSTEP(2, 1)
#undef REDSTEP
    acc_a[0] = __hadd2(acc_a[0], shfl_xor_h2(acc_a[0], 1));
    acc_b[0] = __hadd2(acc_b[0], shfl_xor_h2(acc_b[0], 1));
    if (!(jl & 1)) {
        int d2 = (jl >> 1) & 15;
        int col = h * 32 + d2 * 2;
        float2 oa = make_float2(__low2float(acc_a[0]), __high2float(acc_a[0]));
        float2 ob = make_float2(__low2float(acc_b[0]), __high2float(acc_b[0]));
        *(float2*)&attn_out[(b * SEQ + i0 + g) * IND + col] = oa;
        *(float2*)&attn_out[(b * SEQ + i0 + g + 8) * IND + col] = ob;
    }

    float colp[16];
    #pragma unroll
    for (int m = 0; m < 16; m++) {
        float cp = vals_a[m] + vals_b[m];
        cp += __shfl_xor(cp, 32, 64);
        colp[m] = cp;
    }
    float* amw = (float*)&Th[0][0][0];
    const int w = t >> 6;
    if (!(t & 32)) {
        #pragma unroll
        for (int m = 0; m < 16; m++) {
            int j = (m >> 2) * 128 + (m & 3) * 32 + jl;
            amw[w * 512 + j] = colp[m];
        }
    }
    __syncthreads();
    #pragma unroll
    for (int n = 0; n < 2; n++) {
        int j = t + n * 256;
        float s = (amw[j] + amw[512 + j] + amw[1024 + j] + amw[1536 + j]) * 0.125f;
        atomicAdd(&am[b * SEQ + j], s);
    }
}

// ============ Kernel 3: FC(bf16 MFMA) + residual, + fused amnorm ============
// grid (33, 4): x<32 -> GEMM tile (m0=x*64, n0=y*64); x==32 -> amnorm batch y
__global__ __launch_bounds__(256) void fcam_kernel(
        const float* __restrict__ ao, const float* __restrict__ wfc,
        const float* __restrict__ xn, const float* __restrict__ am,
        float* __restrict__ out, float* __restrict__ out_am) {
    __shared__ __align__(16) unsigned short As[64][264];
    __shared__ __align__(16) unsigned short Bs[2][64][40];
    __shared__ float lmn[4], lmx[4];
    const int t = threadIdx.x;

    if (blockIdx.x == 32) {   // ---- amnorm for batch blockIdx.y ----
        int b = blockIdx.y;
        float v0 = am[b * SEQ + t];
        float v1 = am[b * SEQ + t + 256];
        float mn = fminf(v0, v1), mx = fmaxf(v0, v1);
        #pragma unroll
        for (int o = 32; o > 0; o >>= 1) {
            mn = fminf(mn, __shfl_xor(mn, o, 64));
            mx = fmaxf(mx, __shfl_xor(mx, o, 64));
        }
        int w = t >> 6;
        if ((t & 63) == 0) { lmn[w] = mn; lmx[w] = mx; }
        __syncthreads();
        mn = fminf(fminf(lmn[0], lmn[1]), fminf(lmn[2], lmn[3]));
        mx = fmaxf(fmaxf(lmx[0], lmx[1]), fmaxf(lmx[2], lmx[3]));
        float inv = 1.0f / (mx - mn);
        out_am[b * SEQ + t]       = (v0 - mn) * inv;
        out_am[b * SEQ + t + 256] = (v1 - mn) * inv;
        return;
    }

    const int m0 = blockIdx.x * 64;
    const int n0 = blockIdx.y * 64;

    // ---- Phase A: stage AO tile (f32 -> bf16), full K resident ----
    {
        const int r = t >> 2, q = t & 3;
        const float* ar = ao + (m0 + r) * IND + q * 64;
        #pragma unroll
        for (int i = 0; i < 8; i++) {
            float4 a = *(const float4*)&ar[i * 8];
            float4 bv = *(const float4*)&ar[i * 8 + 4];
            uint4 pk;
            pk.x = f2bf2(a.x, a.y);  pk.y = f2bf2(a.z, a.w);
            pk.z = f2bf2(bv.x, bv.y); pk.w = f2bf2(bv.z, bv.w);
            *(uint4*)&As[r][q * 64 + i * 8] = pk;
        }
    }

    const int w = t >> 6, l = t & 63;
    const int wm = (w >> 1) * 32, wn = (w & 1) * 32;
    const int fr = l & 15, fg = l >> 4;
    floatx4 acc[2][2];
    #pragma unroll
    for (int i = 0; i < 2; i++)
        #pragma unroll
        for (int j = 0; j < 2; j++) acc[i][j] = (floatx4)(0.0f);

    const int kl = t >> 4, nq = t & 15;
    auto stageB = [&](int kt, int buf) {
        float4 b0 = *(const float4*)&wfc[(kt * 32 + kl) * IND + n0 + nq * 4];
        float4 b1 = *(const float4*)&wfc[(kt * 32 + 16 + kl) * IND + n0 + nq * 4];
        Bs[buf][nq * 4 + 0][kl] = (unsigned short)f2bf1(b0.x);
        Bs[buf][nq * 4 + 1][kl] = (unsigned short)f2bf1(b0.y);
        Bs[buf][nq * 4 + 2][kl] = (unsigned short)f2bf1(b0.z);
        Bs[buf][nq * 4 + 3][kl] = (unsigned short)f2bf1(b0.w);
        Bs[buf][nq * 4 + 0][kl + 16] = (unsigned short)f2bf1(b1.x);
        Bs[buf][nq * 4 + 1][kl + 16] = (unsigned short)f2bf1(b1.y);
        Bs[buf][nq * 4 + 2][kl + 16] = (unsigned short)f2bf1(b1.z);
        Bs[buf][nq * 4 + 3][kl + 16] = (unsigned short)f2bf1(b1.w);
    };
    stageB(0, 0);
    __syncthreads();
    #pragma unroll
    for (int kt = 0; kt < 8; kt++) {
        if (kt < 7) stageB(kt + 1, (kt + 1) & 1);
        const int buf = kt & 1;
        short8v a0 = *(const short8v*)&As[wm + fr][kt * 32 + fg * 8];
        short8v a1 = *(const short8v*)&As[wm + 16 + fr][kt * 32 + fg * 8];
        short8v b0 = *(const short8v*)&Bs[buf][wn + fr][fg * 8];
        short8v b1 = *(const short8v*)&Bs[buf][wn + 16 + fr][fg * 8];
        acc[0][0] = __builtin_amdgcn_mfma_f32_16x16x32_bf16(a0, b0, acc[0][0], 0, 0, 0);
        acc[0][1] = __builtin_amdgcn_mfma_f32_16x16x32_bf16(a0, b1, acc[0][1], 0, 0, 0);
        acc[1][0] = __builtin_amdgcn_mfma_f32_16x16x32_bf16(a1, b0, acc[1][0], 0, 0, 0);
        acc[1][1] = __builtin_amdgcn_mfma_f32_16x16x32_bf16(a1, b1, acc[1][1], 0, 0, 0);
        __syncthreads();
    }

    // ---- Epilogue: + residual xn (f32), store f32 ----
    #pragma unroll
    for (int mi = 0; mi < 2; mi++)
        #pragma unroll
        for (int ni = 0; ni < 2; ni++)
            #pragma unroll
            for (int reg = 0; reg < 4; reg++) {
                int row = m0 + wm + mi * 16 + fg * 4 + reg;
                int col = n0 + wn + ni * 16 + fr;
                out[row * IND + col] = acc[mi][ni][reg] + xn[row * IND + col];
            }
}

extern "C" void kernel_launch(void* const* d_in, const int* in_sizes, int n_in,
                              void* d_out, int out_size, void* d_ws, size_t ws_size,
                              hipStream_t stream) {
    (void)in_sizes; (void)n_in; (void)out_size; (void)ws_size;
    const float* x     = (const float*)d_in[0];
    const float* w_q   = (const float*)d_in[1];
    const float* w_k   = (const float*)d_in[2];
    const float* w_v   = (const float*)d_in[3];
    const float* w_fc  = (const float*)d_in[4];
    const float* gamma = (const float*)d_in[5];
    const float* beta  = (const float*)d_in[6];
    float* out = (float*)d_out;

    float* ws = (float*)d_ws;
    float* xn = ws;                          // 2048*256 f32
    float* AO = xn + NTOK * IND;             // 2048*256 f32
    float* AM = AO + NTOK * IND;             // 2048 f32
    __half* Qh = (__half*)(AM + NTOK);       // 32*512*32 f16 each
    __half* Kh = Qh + BH * SEQ * DKV;
    __half* Vh = Kh + BH * SEQ * DKV;

    hipLaunchKernelGGL(lnproj_kernel, dim3(32, 12), dim3(256), 0, stream,
                       x, gamma, beta, w_q, w_k, w_v, xn, AM, Qh, Kh, Vh);
    hipLaunchKernelGGL(attn_kernel, dim3(SEQ / 16, BH), dim3(256), 0, stream,
                       Qh, Kh, Vh, AO, AM);
    hipLaunchKernelGGL(fcam_kernel, dim3(33, 4), dim3(256), 0, stream,
                       AO, w_fc, xn, AM, out, out + NTOK * IND);
}